// Round 14
// baseline (96.449 us; speedup 1.0000x reference)
//
#include <hip/hip_runtime.h>
#include <stdint.h>

// RadialAEVComputer: out[b,i,s*16+p] = sum_{j: 0<d<RC, spc(j)=s} exp(-16(d-shf_p)^2)*fc(d)
// B=64, N=256, S=4, P=16, RC=5.2, shf_p = 0.9 + 0.26875*p
// d_in[0]: fp32 [B,256,256]; d_in[1]: int32 [B,256] (1..4); d_out: fp32 [B,256,64]
//
// Block = 256 = 4 fully independent waves (NO __syncthreads), 2 rows/wave,
// grid = B*32 = 2048 (8 blocks/CU x 256 CU, single generation).
// Phase B (per row): validity+species ballot-rank compaction (R8-proven) of
//   (cA = K*d^2 + log2(fc), cB = -2K*d) into ragged species segments (~77
//   pairs/row instead of 256). Masks are wave-uniform -> SGPRs.
// Phase C: lane=(g,q',s'); per pair+row: E=exp2(X(p0)), T=exp2(dX(p0)), then
//   the 4 shifts via the ladder E*=T, T*=q (q=exp2(2K*delta^2) const):
//   2 trans + ~12 VALU per pair-row (was 4 trans + 12). Tails masked by
//   cA=-inf AND cB=0 selects. Quad shfl reduce; coalesced nt stores.

static __device__ __forceinline__ int mbcnt64(uint64_t m) {
    int lo = __builtin_amdgcn_mbcnt_lo((uint32_t)m, 0u);
    return __builtin_amdgcn_mbcnt_hi((uint32_t)(m >> 32), lo);
}

typedef float vfloat2 __attribute__((ext_vector_type(2)));
typedef float vfloat4 __attribute__((ext_vector_type(4)));

#define KNEG  (-23.083120654223414f)   /* -16*log2(e) */
#define DELTA (0.26875f)

__global__ __launch_bounds__(256, 8) void aev_kernel(
    const float* __restrict__ dmat,      // fp32 [B,256,256]
    const int* __restrict__ species,     // int32 [B,256], values 1..4
    float* __restrict__ out)             // fp32 [B,256,64]
{
    __shared__ alignas(16) float2 comp[8][260];  // per-row compacted (cA, cB)
    __shared__ alignas(16) float  red[8][64];    // per-row [s*16+p] results

    const int tid  = threadIdx.x;
    const int w    = tid >> 6;
    const int lane = tid & 63;
    const int blk  = (int)blockIdx.x;
    const int row0 = blk * 8 + w * 2;    // this wave's rows: row0, row0+1
    const int b    = blk >> 5;
    const int lr   = w * 2;

    // ---- issue both global row loads immediately (nontemporal) ----
    const vfloat4 qa = __builtin_nontemporal_load(
        (const vfloat4*)(dmat + ((size_t)row0 << 8)) + lane);
    const vfloat4 qb = __builtin_nontemporal_load(
        (const vfloat4*)(dmat + ((size_t)(row0 + 1) << 8)) + lane);

    // ---- species of j = 4*lane+e (row-independent, wave-local) ----
    const int4 s4 = ((const int4*)(species + (b << 8)))[lane];
    int sv[4] = {s4.x - 1, s4.y - 1, s4.z - 1, s4.w - 1};
    #pragma unroll
    for (int e = 0; e < 4; ++e) sv[e] = (sv[e] < 0) ? 0 : ((sv[e] > 3) ? 3 : sv[e]);

    // per-element-slot species lane masks (wave-uniform -> SGPR pairs)
    uint64_t sm[4][4];
    #pragma unroll
    for (int e = 0; e < 4; ++e) {
        const uint64_t c0 = __ballot((sv[e] & 1) != 0);
        const uint64_t c1 = __ballot((sv[e] & 2) != 0);
        sm[e][0] = ~c0 & ~c1; sm[e][1] = c0 & ~c1;
        sm[e][2] = ~c0 &  c1; sm[e][3] = c0 &  c1;
    }

    const float dv0[4] = {qa.x, qa.y, qa.z, qa.w};
    const float dv1[4] = {qb.x, qb.y, qb.z, qb.w};
    const float NINF = -__builtin_inff();
    int sb[2][5];

    // ---- phase B: per-row validity compaction + (cA, cB) scatter ----
    #pragma unroll
    for (int r = 0; r < 2; ++r) {
        // pass 1: validity ballots + species counts (all scalar-side)
        uint64_t bvE[4];
        int cnt[4] = {0, 0, 0, 0};
        #pragma unroll
        for (int e = 0; e < 4; ++e) {
            const float dd = (r == 0) ? dv0[e] : dv1[e];
            bvE[e] = __ballot((dd < 5.2f) && (dd != 0.0f));   // false for NaN
            #pragma unroll
            for (int s = 0; s < 4; ++s) cnt[s] += __popcll(bvE[e] & sm[e][s]);
        }
        sb[r][0] = 0;
        #pragma unroll
        for (int s = 0; s < 4; ++s) sb[r][s + 1] = sb[r][s] + cnt[s];

        // pass 2: rank + scatter
        int run[4] = {sb[r][0], sb[r][1], sb[r][2], sb[r][3]};
        #pragma unroll
        for (int e = 0; e < 4; ++e) {
            const float dd = (r == 0) ? dv0[e] : dv1[e];
            const bool  v  = (dd < 5.2f) && (dd != 0.0f);
            const float x  = v ? dd : 2.6f;                  // cos arg in-domain
            // fc = 0.5*cos(pi*d/RC)+0.5 ; v_cos takes revolutions: x/(2*RC)
            const float fc = 0.5f * __builtin_amdgcn_cosf(x * (0.5f / 5.2f)) + 0.5f;
            const float cA = __builtin_fmaf(KNEG * x, x, __builtin_amdgcn_logf(fc));
            const float cB = (-2.0f * KNEG) * x;
            const int s = sv[e];
            uint64_t msel = bvE[e] & sm[e][0];
            msel = (s == 1) ? (bvE[e] & sm[e][1]) : msel;
            msel = (s == 2) ? (bvE[e] & sm[e][2]) : msel;
            msel = (s == 3) ? (bvE[e] & sm[e][3]) : msel;
            int base = run[0];
            base = (s == 1) ? run[1] : base;
            base = (s == 2) ? run[2] : base;
            base = (s == 3) ? run[3] : base;
            const int slot0 = base + mbcnt64(msel);
            const int slot  = (slot0 < 259) ? slot0 : 259;   // insurance
            if (v) comp[lr + r][slot] = make_float2(cA, cB);
            #pragma unroll
            for (int s2 = 0; s2 < 4; ++s2) run[s2] += __popcll(bvE[e] & sm[e][s2]);
        }
    }
    // no __syncthreads: comp[lr..lr+1] is wave-private; compiler orders LDS ops

    // ---- phase C: lane = g*16 + q'*4 + s' ----
    const int g  = lane >> 4;            // 0..3 -> shifts p = 4g..4g+3
    const int qp = (lane >> 2) & 3;      // quad slot within segment
    const int sp = lane & 3;             // owned species segment

    const float sh0 = 0.9f + DELTA * (float)(4 * g);
    const float kp0 = KNEG * sh0 * sh0;
    const float dc0 = KNEG * DELTA * (2.0f * sh0 + DELTA);   // dX(p0) = fma(DELTA, cB, dc0)
    const float qc  = __builtin_amdgcn_exp2f(2.0f * KNEG * DELTA * DELTA);  // ladder ratio ratio

    const int sbeg0 = (sp == 0) ? sb[0][0] : (sp == 1) ? sb[0][1] : (sp == 2) ? sb[0][2] : sb[0][3];
    const int send0 = (sp == 0) ? sb[0][1] : (sp == 1) ? sb[0][2] : (sp == 2) ? sb[0][3] : sb[0][4];
    const int sbeg1 = (sp == 0) ? sb[1][0] : (sp == 1) ? sb[1][1] : (sp == 2) ? sb[1][2] : sb[1][3];
    const int send1 = (sp == 0) ? sb[1][1] : (sp == 1) ? sb[1][2] : (sp == 2) ? sb[1][3] : sb[1][4];

    int ml = 0;
    #pragma unroll
    for (int r = 0; r < 2; ++r)
        #pragma unroll
        for (int s = 0; s < 4; ++s) {
            const int L = sb[r][s + 1] - sb[r][s];
            ml = (L > ml) ? L : ml;
        }
    const int nIt = (ml + 3) >> 2;       // wave-uniform

    float a0x = 0.f, a0y = 0.f, a0z = 0.f, a0w = 0.f;
    float a1x = 0.f, a1y = 0.f, a1z = 0.f, a1w = 0.f;
    for (int m = 0; m < nIt; ++m) {
        const int k0 = sbeg0 + qp + 4 * m;
        const int k1 = sbeg1 + qp + 4 * m;
        const int k0c = (k0 < 259) ? k0 : 259;
        const int k1c = (k1 < 259) ? k1 : 259;
        const float2 u0 = comp[lr][k0c];
        const float2 u1 = comp[lr + 1][k1c];
        const bool l0 = (k0 < send0);
        const bool l1 = (k1 < send1);
        const float A0 = l0 ? u0.x : NINF;   // -inf -> whole ladder = 0
        const float B0 = l0 ? u0.y : 0.0f;   // keep fma finite (never NaN)
        const float A1 = l1 ? u1.x : NINF;
        const float B1 = l1 ? u1.y : 0.0f;

        float E0 = __builtin_amdgcn_exp2f(__builtin_fmaf(B0, sh0, A0) + kp0);
        float T0 = __builtin_amdgcn_exp2f(__builtin_fmaf(DELTA, B0, dc0));
        a0x += E0; E0 *= T0; T0 *= qc;
        a0y += E0; E0 *= T0; T0 *= qc;
        a0z += E0; E0 *= T0;
        a0w += E0;

        float E1 = __builtin_amdgcn_exp2f(__builtin_fmaf(B1, sh0, A1) + kp0);
        float T1 = __builtin_amdgcn_exp2f(__builtin_fmaf(DELTA, B1, dc0));
        a1x += E1; E1 *= T1; T1 *= qc;
        a1y += E1; E1 *= T1; T1 *= qc;
        a1z += E1; E1 *= T1;
        a1w += E1;
    }

    // ---- reduce over q' (lanes xor 4, 8) ----
    #pragma unroll
    for (int d = 4; d <= 8; d <<= 1) {
        a0x += __shfl_xor(a0x, d, 64); a0y += __shfl_xor(a0y, d, 64);
        a0z += __shfl_xor(a0z, d, 64); a0w += __shfl_xor(a0w, d, 64);
        a1x += __shfl_xor(a1x, d, 64); a1y += __shfl_xor(a1y, d, 64);
        a1z += __shfl_xor(a1z, d, 64); a1w += __shfl_xor(a1w, d, 64);
    }

    // lanes with q'==0 hold the (g, s') sums: write [s'*16 + 4g .. +3]
    if (qp == 0) {
        float4* r0 = (float4*)&red[lr][(sp << 4) + (g << 2)];
        float4* r1 = (float4*)&red[lr + 1][(sp << 4) + (g << 2)];
        *r0 = make_float4(a0x, a0y, a0z, a0w);
        *r1 = make_float4(a1x, a1y, a1z, a1w);
    }

    // ---- store: wave gathers its own rows from red (wave-synchronous) ----
    {
        const int r  = lane >> 5;                   // 0..1
        const int c2 = lane & 31;                   // float2 column
        const float2 rv = ((const float2*)&red[lr + r][0])[c2];
        vfloat2 nv; nv.x = rv.x; nv.y = rv.y;
        vfloat2* dst = (vfloat2*)&out[((size_t)(row0 + r) << 6) + (size_t)(c2 * 2)];
        __builtin_nontemporal_store(nv, dst);
    }
}

extern "C" void kernel_launch(void* const* d_in, const int* in_sizes, int n_in,
                              void* d_out, int out_size, void* d_ws, size_t ws_size,
                              hipStream_t stream) {
    const float* dmat  = (const float*)d_in[0];          // fp32 [B,256,256]
    const int* species = (const int*)d_in[1];            // int32 [B,256]
    float* o           = (float*)d_out;                  // fp32 [B,256,64]
    const int B = in_sizes[1] >> 8;                      // N = 256
    aev_kernel<<<dim3(B * 32), 256, 0, stream>>>(dmat, species, o);
}

// Round 15
// 75.118 us; speedup vs baseline: 1.2840x; 1.2840x over previous
//
#include <hip/hip_runtime.h>
#include <stdint.h>

// RadialAEVComputer: out[b,i,s*16+p] = sum_{j: 0<d<RC, spc(j)=s} exp(-16(d-shf_p)^2)*fc(d)
// B=64, N=256, S=4, P=16, RC=5.2, shf_p = 0.9 + 0.26875*p
// d_in[0]: fp32 [B,256,256]; d_in[1]: int32 [B,256] (1..4); d_out: fp32 [B,256,64]
//
// Best-measured configuration (R13, 75.7 us): block = 256 = 4 waves, 2 rows/
// wave, grid = B*32 = 2048, __launch_bounds__(256,8), nontemporal dmat loads.
// The kernel window is bound by the harness's 256MB poison-drain sharing the
// memory system (R8 counters: 130MB background writes in-window); compute-side
// changes are neutral, so this is the minimal-risk best artifact.
// Phase A: per-b species permutation (2 ballots, exact bijection).
// Phase B: stage (cA = K*d^2 + log2(fc*mask), cB = -2K*d); invalid -> cA=-inf.
// Phase C: lane=(g,q',s'): term = exp2(fma(cB, shf, cA) + K*shf^2); 8 exps
//          per LDS pair read; quad shfl reduce; coalesced nt stores.

static __device__ __forceinline__ int mbcnt64(uint64_t m) {
    int lo = __builtin_amdgcn_mbcnt_lo((uint32_t)m, 0u);
    return __builtin_amdgcn_mbcnt_hi((uint32_t)(m >> 32), lo);
}

typedef float vfloat2 __attribute__((ext_vector_type(2)));
typedef float vfloat4 __attribute__((ext_vector_type(4)));

#define KNEG (-23.083120654223414f)   /* -16*log2(e) */

__global__ __launch_bounds__(256, 8) void aev_kernel(
    const float* __restrict__ dmat,      // fp32 [B,256,256]
    const int* __restrict__ species,     // int32 [B,256], values 1..4
    float* __restrict__ out)             // fp32 [B,256,64]
{
    __shared__ alignas(16) float2 comp[8][256]; // per-row permuted (cA, cB)
    __shared__ alignas(16) int    pos[256];     // species-major permutation of j
    __shared__ alignas(16) float  red[8][64];   // per-row [s*16+p] results
    __shared__ int cntm[4][4];                  // per-wave per-species counts

    const int tid  = threadIdx.x;
    const int w    = tid >> 6;
    const int lane = tid & 63;
    const int blk  = (int)blockIdx.x;
    const int row0 = blk * 8 + w * 2;    // this wave's rows: row0, row0+1
    const int b    = blk >> 5;

    // ---- issue both global row loads immediately (nontemporal: skip L3) ----
    const vfloat4 qa = __builtin_nontemporal_load(
        (const vfloat4*)(dmat + ((size_t)row0 << 8)) + lane);
    const vfloat4 qb = __builtin_nontemporal_load(
        (const vfloat4*)(dmat + ((size_t)(row0 + 1) << 8)) + lane);

    // ---- phase A: per-b species permutation ----
    int sj = species[(b << 8) + tid] - 1;           // 0..3
    sj = (sj < 0) ? 0 : ((sj > 3) ? 3 : sj);        // insurance
    const uint64_t bs0 = __ballot((sj & 1) != 0);
    const uint64_t bs1 = __ballot((sj & 2) != 0);
    const uint64_t m0 = ~bs0 & ~bs1, m1 = bs0 & ~bs1;
    const uint64_t m2 = ~bs0 &  bs1, m3 = bs0 &  bs1;
    if (lane == 0) {
        cntm[w][0] = __popcll(m0); cntm[w][1] = __popcll(m1);
        cntm[w][2] = __popcll(m2); cntm[w][3] = __popcll(m3);
    }
    uint64_t msel = m0;
    msel = (sj == 1) ? m1 : msel;
    msel = (sj == 2) ? m2 : msel;
    msel = (sj == 3) ? m3 : msel;
    const int rank = mbcnt64(msel);
    __syncthreads();

    // wave-uniform segment bases -> force into SGPRs
    int seg[5];
    seg[0] = 0;
    #pragma unroll
    for (int s = 0; s < 4; ++s)
        seg[s + 1] = __builtin_amdgcn_readfirstlane(
            seg[s] + cntm[0][s] + cntm[1][s] + cntm[2][s] + cntm[3][s]);
    {
        int base = seg[0];
        base = (sj == 1) ? seg[1] : base;
        base = (sj == 2) ? seg[2] : base;
        base = (sj == 3) ? seg[3] : base;
        int wadd = 0;
        #pragma unroll
        for (int w2 = 0; w2 < 3; ++w2) wadd += (w2 < w) ? cntm[w2][sj] : 0;
        pos[tid] = base + wadd + rank;              // exact bijection [0,256)
    }
    __syncthreads();

    // ---- phase B: stage both rows as (cA, cB), permuted ----
    {
        const int4 p4 = *(const int4*)&pos[4 * lane];
        const int   pp[4] = {p4.x, p4.y, p4.z, p4.w};
        const float da[4] = {qa.x, qa.y, qa.z, qa.w};
        const float db[4] = {qb.x, qb.y, qb.z, qb.w};
        const float NINF = -__builtin_inff();
        const int lr = w * 2;
        #pragma unroll
        for (int e = 0; e < 4; ++e) {
            const float dd = da[e];
            const bool  v  = (dd < 5.2f) && (dd != 0.0f);   // false for NaN
            const float x  = v ? dd : 2.6f;                 // cos arg in-domain
            const float fc = 0.5f * __builtin_amdgcn_cosf(x * (0.5f / 5.2f)) + 0.5f;
            const float cA = __builtin_fmaf(KNEG * x, x, __builtin_amdgcn_logf(fc));
            comp[lr][pp[e]] = make_float2(v ? cA : NINF, v ? (-2.0f * KNEG) * x : 0.0f);
        }
        #pragma unroll
        for (int e = 0; e < 4; ++e) {
            const float dd = db[e];
            const bool  v  = (dd < 5.2f) && (dd != 0.0f);
            const float x  = v ? dd : 2.6f;
            const float fc = 0.5f * __builtin_amdgcn_cosf(x * (0.5f / 5.2f)) + 0.5f;
            const float cA = __builtin_fmaf(KNEG * x, x, __builtin_amdgcn_logf(fc));
            comp[lr + 1][pp[e]] = make_float2(v ? cA : NINF, v ? (-2.0f * KNEG) * x : 0.0f);
        }
    }
    __syncthreads();

    // ---- phase C: lane = g*16 + q'*4 + s' ----
    const int g  = lane >> 4;            // 0..3 -> shifts p = 4g..4g+3
    const int qp = (lane >> 2) & 3;      // quad slot within segment
    const int sp = lane & 3;             // owned species segment
    const int lr = w * 2;

    const float shf0 = 0.9f + 0.26875f * (float)(4 * g);   // shf[t] = shf0 + 0.26875*t

    const int sbeg = (sp == 0) ? seg[0] : (sp == 1) ? seg[1] : (sp == 2) ? seg[2] : seg[3];
    const int send = (sp == 0) ? seg[1] : (sp == 1) ? seg[2] : (sp == 2) ? seg[3] : seg[4];
    int maxLen = seg[1] - seg[0];
    maxLen = (seg[2] - seg[1] > maxLen) ? seg[2] - seg[1] : maxLen;
    maxLen = (seg[3] - seg[2] > maxLen) ? seg[3] - seg[2] : maxLen;
    maxLen = (seg[4] - seg[3] > maxLen) ? seg[4] - seg[3] : maxLen;
    const int nIt = __builtin_amdgcn_readfirstlane((maxLen + 3) >> 2);

    const float NINF = -__builtin_inff();
    float a0x = 0.f, a0y = 0.f, a0z = 0.f, a0w = 0.f;   // row0, t=0..3
    float a1x = 0.f, a1y = 0.f, a1z = 0.f, a1w = 0.f;   // row1
    for (int m = 0; m < nIt; ++m) {
        const int k  = sbeg + qp + 4 * m;
        const int kc = (k < 255) ? k : 255;
        const bool live = (k < send);
        const float2 cR0 = comp[lr][kc];
        const float2 cR1 = comp[lr + 1][kc];
        const float A0 = live ? cR0.x : NINF;
        const float A1 = live ? cR1.x : NINF;
        // term = exp2(cB*shf + cA + K*shf^2); dead lanes/tails -> exp2(-inf)=0
        #pragma unroll
        for (int t = 0; t < 4; ++t) {
            const float sh = shf0 + 0.26875f * (float)t;    // rematerialized
            const float kp = KNEG * sh * sh;
            const float e0 = __builtin_amdgcn_exp2f(__builtin_fmaf(cR0.y, sh, A0) + kp);
            const float e1 = __builtin_amdgcn_exp2f(__builtin_fmaf(cR1.y, sh, A1) + kp);
            if (t == 0) { a0x += e0; a1x += e1; }
            if (t == 1) { a0y += e0; a1y += e1; }
            if (t == 2) { a0z += e0; a1z += e1; }
            if (t == 3) { a0w += e0; a1w += e1; }
        }
    }

    // ---- reduce over q' (lanes xor 4, 8) ----
    #pragma unroll
    for (int d = 4; d <= 8; d <<= 1) {
        a0x += __shfl_xor(a0x, d, 64); a0y += __shfl_xor(a0y, d, 64);
        a0z += __shfl_xor(a0z, d, 64); a0w += __shfl_xor(a0w, d, 64);
        a1x += __shfl_xor(a1x, d, 64); a1y += __shfl_xor(a1y, d, 64);
        a1z += __shfl_xor(a1z, d, 64); a1w += __shfl_xor(a1w, d, 64);
    }

    // lanes with q'==0 hold the (g, s') sums: write [s'*16 + 4g .. +3]
    if (qp == 0) {
        float4* r0 = (float4*)&red[lr][(sp << 4) + (g << 2)];
        float4* r1 = (float4*)&red[lr + 1][(sp << 4) + (g << 2)];
        *r0 = make_float4(a0x, a0y, a0z, a0w);
        *r1 = make_float4(a1x, a1y, a1z, a1w);
    }

    // ---- store: wave reads its own rows from red (wave-synchronous) ----
    {
        const int r  = lane >> 5;                   // 0..1 (this wave's rows)
        const int c2 = lane & 31;                   // float2 column
        const float2 rv = ((const float2*)&red[lr + r][0])[c2];
        vfloat2 nv; nv.x = rv.x; nv.y = rv.y;
        vfloat2* dst = (vfloat2*)&out[((size_t)(row0 + r) << 6) + (size_t)(c2 * 2)];
        __builtin_nontemporal_store(nv, dst);
    }
}

extern "C" void kernel_launch(void* const* d_in, const int* in_sizes, int n_in,
                              void* d_out, int out_size, void* d_ws, size_t ws_size,
                              hipStream_t stream) {
    const float* dmat  = (const float*)d_in[0];          // fp32 [B,256,256]
    const int* species = (const int*)d_in[1];            // int32 [B,256]
    float* o           = (float*)d_out;                  // fp32 [B,256,64]
    const int B = in_sizes[1] >> 8;                      // N = 256
    aev_kernel<<<dim3(B * 32), 256, 0, stream>>>(dmat, species, o);
}